// Round 1
// 384.826 us; speedup vs baseline: 1.0049x; 1.0049x over previous
//
#include <hip/hip_runtime.h>
#include <cmath>

// DPI neuron forward: spike = (max(Imem + dImem, I0) > SPIKE_TH).
// R1: VALU-bound (65% busy) -- 3 f32 div expansions + powf.
// R3: division-free product comparison -> VALUBusy 7%, dur 150us.
// R4: grid-stride unroll-4 + nontemporal -> 99.7us kernel.
// R5 (this round): counter forensics -- FETCH_SIZE is EXACTLY half of logical
//     reads while WRITE_SIZE matches exactly => gfx94x-fallback formula
//     undercounts gfx950 reads 2x. True BW = 537MB/99.7us = 5.39 TB/s = 86%
//     of the 6.29 TB/s copy ceiling. Remaining loss theory: at 32 VGPRs the
//     compiler can't pipeline across iterations (7 loads -> vmcnt(0) ->
//     compute -> store; zero loads in flight during compute). Fix: manual
//     2-stage pipeline (prefetch all 7 streams of chunk k+1 before computing
//     chunk k), __launch_bounds__(256,6) to cap VGPR ~84 (24 waves/CU),
//     block-contiguous chunk mapping (imm +4KB offsets, DRAM page locality).
//
// Math (from R2, unchanged): all divisors provably positive, so
//   dImem > TH - Imem  <=>  im*(A*t + p*img) > (TH-im)*(tau/DT)*img*t
// with t = (1+exp(-ALPHA*(im-IGAIN)))*Ileak > 0,
//      p = I0^(1/(k+1)) * im^(k/(k+1))  (v_log_f32 + fma + v_exp_f32),
//      A = (IGAIN/ITAU)*(Iin-Ileak) - im*(1 + ah/ITAU),  img = im + IGAIN.
// >9 decades of sign margin over the whole input range => 1-ulp hw log2/exp2
// and the rearrangement cannot flip the Heaviside output.

namespace {
constexpr float F_I0    = 0.5e-13f;
constexpr float F_ITAU  = 4.25e-12f;   // ITAU_MEM
constexpr float F_IGAIN = 5.965e-11f;  // IGAIN_MEM
constexpr float F_TH    = 0.00015f;    // SPIKE_TH
constexpr int   CPB     = 4;           // float4-chunks per thread; block span = 256*CPB
}

typedef float f32x4 __attribute__((ext_vector_type(4)));

struct DpiC {
    float kexp;            // k/(k+1)
    float l2_i0pow;        // log2(I0)/(k+1)
    float nalpha_l2e;      // -ALPHA * log2(e)
    float alpha_igain_l2e; //  ALPHA * IGAIN * log2(e)
    float gain_over_tau;   // IGAIN/ITAU
    float inv_itau;        // 1/ITAU
    float tau_over_dt;     // TAU_MEM/DT
};

__device__ __forceinline__ float dpi_spike(float im, float ah, float tr, float am,
                                           float nm, float sh, float gb, DpiC c) {
    float iin = (am + nm) - sh;
    iin = (tr <= 0.0f) ? iin : 0.0f;       // refractory mask (IDC == 0)
    iin = fmaxf(iin, F_I0);
    float ileak = (F_ITAU + ah) + gb;
    float img   = im + F_IGAIN;
    float p = __builtin_amdgcn_exp2f(fmaf(c.kexp, __builtin_amdgcn_logf(im), c.l2_i0pow));
    float e = 1.0f + __builtin_amdgcn_exp2f(fmaf(c.nalpha_l2e, im, c.alpha_igain_l2e));
    float t = e * ileak;                    // > 0
    float A = fmaf(c.gain_over_tau, iin - ileak, -im * fmaf(ah, c.inv_itau, 1.0f));
    float lhs = im * fmaf(A, t, p * img);
    float rhs = (F_TH - im) * (c.tau_over_dt * (img * t));
    return (lhs > rhs) ? 1.0f : 0.0f;
}

__device__ __forceinline__ f32x4 dpi_spike4(const f32x4& im, const f32x4& ah, const f32x4& tr,
                                            const f32x4& am, const f32x4& nm, const f32x4& sh,
                                            const f32x4& gb, DpiC c) {
    f32x4 o;
    o.x = dpi_spike(im.x, ah.x, tr.x, am.x, nm.x, sh.x, gb.x, c);
    o.y = dpi_spike(im.y, ah.y, tr.y, am.y, nm.y, sh.y, gb.y, c);
    o.z = dpi_spike(im.z, ah.z, tr.z, am.z, nm.z, sh.z, gb.z, c);
    o.w = dpi_spike(im.w, ah.w, tr.w, am.w, nm.w, sh.w, gb.w, c);
    return o;
}

// __launch_bounds__(256, 6): 6 waves/SIMD min -> VGPR cap ~84. Pipeline needs
// ~14 float4 live (56 VGPR) + addressing/temps; 24 waves/CU >= R4's 21.6.
__global__ void __launch_bounds__(256, 6)
dpi_neuron_kernel(const f32x4* __restrict__ Imem,
                  const f32x4* __restrict__ Iahp,
                  const f32x4* __restrict__ timer_ref,
                  const f32x4* __restrict__ Iampa,
                  const f32x4* __restrict__ Inmda,
                  const f32x4* __restrict__ Ishunt,
                  const f32x4* __restrict__ Igaba,
                  f32x4* __restrict__ out,
                  int n4, int n_total, DpiC c) {
    const int t = threadIdx.x;
    const long long base_ll = (long long)blockIdx.x * (256 * CPB);

    if (base_ll + 256 * CPB <= (long long)n4) {
        // Fast path: block owns a full contiguous span of 256*CPB float4s.
        // 2-stage pipeline: chunk k+1's 7 loads issue before chunk k's compute,
        // so every wave keeps 7 loads in flight through its compute phase.
        int i = (int)base_ll + t;
        f32x4 im = __builtin_nontemporal_load(&Imem[i]);
        f32x4 ah = __builtin_nontemporal_load(&Iahp[i]);
        f32x4 tr = __builtin_nontemporal_load(&timer_ref[i]);
        f32x4 am = __builtin_nontemporal_load(&Iampa[i]);
        f32x4 nm = __builtin_nontemporal_load(&Inmda[i]);
        f32x4 sh = __builtin_nontemporal_load(&Ishunt[i]);
        f32x4 gb = __builtin_nontemporal_load(&Igaba[i]);
        #pragma unroll
        for (int k = 0; k < CPB - 1; ++k) {
            const int j = i + 256;
            f32x4 im2 = __builtin_nontemporal_load(&Imem[j]);
            f32x4 ah2 = __builtin_nontemporal_load(&Iahp[j]);
            f32x4 tr2 = __builtin_nontemporal_load(&timer_ref[j]);
            f32x4 am2 = __builtin_nontemporal_load(&Iampa[j]);
            f32x4 nm2 = __builtin_nontemporal_load(&Inmda[j]);
            f32x4 sh2 = __builtin_nontemporal_load(&Ishunt[j]);
            f32x4 gb2 = __builtin_nontemporal_load(&Igaba[j]);
            f32x4 o = dpi_spike4(im, ah, tr, am, nm, sh, gb, c);
            __builtin_nontemporal_store(o, &out[i]);
            im = im2; ah = ah2; tr = tr2; am = am2; nm = nm2; sh = sh2; gb = gb2;
            i = j;
        }
        f32x4 o = dpi_spike4(im, ah, tr, am, nm, sh, gb, c);
        __builtin_nontemporal_store(o, &out[i]);
    } else {
        // Guarded remainder block (dead at the bench shape: 4096*1024 == n4).
        for (int k = 0; k < CPB; ++k) {
            int i = (int)base_ll + k * 256 + t;
            if (i < n4) {
                f32x4 im = __builtin_nontemporal_load(&Imem[i]);
                f32x4 ah = __builtin_nontemporal_load(&Iahp[i]);
                f32x4 tr = __builtin_nontemporal_load(&timer_ref[i]);
                f32x4 am = __builtin_nontemporal_load(&Iampa[i]);
                f32x4 nm = __builtin_nontemporal_load(&Inmda[i]);
                f32x4 sh = __builtin_nontemporal_load(&Ishunt[i]);
                f32x4 gb = __builtin_nontemporal_load(&Igaba[i]);
                f32x4 o = dpi_spike4(im, ah, tr, am, nm, sh, gb, c);
                __builtin_nontemporal_store(o, &out[i]);
            }
        }
    }
    // Scalar tail (dead for n_total divisible by 4, kept for generality).
    if (blockIdx.x == 0 && t == 0) {
        const float* sIm = (const float*)Imem;  const float* sAh = (const float*)Iahp;
        const float* sTr = (const float*)timer_ref; const float* sAm = (const float*)Iampa;
        const float* sNm = (const float*)Inmda; const float* sSh = (const float*)Ishunt;
        const float* sGb = (const float*)Igaba; float* sOut = (float*)out;
        for (int j = n4 * 4; j < n_total; ++j)
            sOut[j] = dpi_spike(sIm[j], sAh[j], sTr[j], sAm[j], sNm[j], sSh[j], sGb[j], c);
    }
}

extern "C" void kernel_launch(void* const* d_in, const int* in_sizes, int n_in,
                              void* d_out, int out_size, void* d_ws, size_t ws_size,
                              hipStream_t stream) {
    // inputs: 0 input(unused), 1 W_ampa(unused), 2 Imem, 3 Iahp, 4 timer_ref,
    //         5 Iampa, 6 Inmda, 7 Ishunt, 8 Igaba
    const f32x4* Imem   = (const f32x4*)d_in[2];
    const f32x4* Iahp   = (const f32x4*)d_in[3];
    const f32x4* tref   = (const f32x4*)d_in[4];
    const f32x4* Iampa  = (const f32x4*)d_in[5];
    const f32x4* Inmda  = (const f32x4*)d_in[6];
    const f32x4* Ishunt = (const f32x4*)d_in[7];
    const f32x4* Igaba  = (const f32x4*)d_in[8];
    f32x4* out = (f32x4*)d_out;

    const double KAPPA = (0.75 + 0.66) / 2.0;    // 0.705
    const double I0 = 0.5e-13, ITAU = 4.25e-12, IGAIN = 5.965e-11;
    const double ALPHA = 1.47e9, DT = 1e-3;
    const double TAU_MEM = 3e-12 * 25.0e-3 / (KAPPA * ITAU);
    const double LOG2E = 1.4426950408889634;

    DpiC c;
    c.kexp            = (float)(KAPPA / (KAPPA + 1.0));
    c.l2_i0pow        = (float)(std::log2(I0) / (KAPPA + 1.0));
    c.nalpha_l2e      = (float)(-ALPHA * LOG2E);
    c.alpha_igain_l2e = (float)( ALPHA * IGAIN * LOG2E);
    c.gain_over_tau   = (float)(IGAIN / ITAU);
    c.inv_itau        = (float)(1.0 / ITAU);
    c.tau_over_dt     = (float)(TAU_MEM / DT);

    int n4 = out_size / 4;
    // Block-contiguous spans: 4096 blocks x 256 threads x 4 chunks at the
    // bench shape (n4 = 4.19M) -- exact cover, all blocks on the fast path.
    int blocks = (n4 + 256 * CPB - 1) / (256 * CPB);
    if (blocks < 1) blocks = 1;
    hipLaunchKernelGGL(dpi_neuron_kernel, dim3(blocks), dim3(256), 0, stream,
                       Imem, Iahp, tref, Iampa, Inmda, Ishunt, Igaba, out,
                       n4, out_size, c);
}